// Round 6
// baseline (67.213 us; speedup 1.0000x reference)
//
#include <hip/hip_runtime.h>

#define NPTS 8192
#define THREADS 256
#define PGRPS 128                   // point-groups of 64 points
#define NBLK (6 * PGRPS)            // 768 compute blocks
#define PLANE (3 * NPTS)            // 24576 floats per (pred|target) plane
#define DEI_N (2 * PLANE)           // 49152 deinterleaved floats
#define K0BLKS (DEI_N / THREADS)    // 192

// ws layout (floats): dei[2][3][NPTS] | partials[NBLK] | counter (1 uint)
#define WS_PARTIALS DEI_N
#define WS_COUNTER  (DEI_N + NBLK)

// K0: deinterleave [N][3] -> [3][N] for both arrays (so candidate loads are
// contiguous & wave-uniform -> s_load), and zero the completion counter
// (fresh every call: poison/replay-safe).
__global__ __launch_bounds__(THREADS) void dei_kernel(
    const float* __restrict__ pred, const float* __restrict__ target,
    float* __restrict__ ws)
{
    const int e   = blockIdx.x * THREADS + threadIdx.x;   // 0..49151
    const int arr = e / PLANE;
    const int r   = e - arr * PLANE;
    const int i   = r / 3;                                // magic-div
    const int ch  = r - i * 3;
    ws[arr * PLANE + ch * NPTS + i] = (arr ? target : pred)[r];
    if (e == 0) ((unsigned int*)ws)[WS_COUNTER] = 0u;
}

// A: block = (ch,dir) x 64-point group. Thread: lane -> point, wave ->
// candidate quarter (2048). Candidates read as wave-UNIFORM float4 from the
// deinterleaved plane -> compiler scalarizes to s_load_dwordx4 (scalar pipe,
// zero LDS). Inner: 4x v_sub_f32(sgpr,v) + 2x v_min3(|.|,|.|) = 1.5 VALU/pair.
// Last-done block (device-scope counter) sums the 768 partials -> out.
__global__ __launch_bounds__(THREADS) void chamfer_kernel(
    const float* __restrict__ dei, float* __restrict__ partials,
    unsigned int* __restrict__ counter, float* __restrict__ out)
{
    const int b   = blockIdx.x;
    const int pg  = b & (PGRPS - 1);
    const int c   = b >> 7;           // 0..5
    const int dir = c & 1;
    const int ch  = c >> 1;

    const float* candc = dei + (dir ? 0 : PLANE) + ch * NPTS;  // other array
    const float* ptsc  = dei + (dir ? PLANE : 0) + ch * NPTS;  // own array

    const int t = threadIdx.x, lane = t & 63, wave = t >> 6;

    const float x = ptsc[pg * 64 + lane];                 // coalesced

    const float4* c4 = (const float4*)candc + wave * (2048 / 4);
    float m0 = 3.0e38f, m1 = 3.0e38f;
    #pragma unroll 8
    for (int k = 0; k < 512; ++k) {
        const float4 cv = c4[k];                          // uniform -> s_load
        m0 = fminf(m0, fminf(fabsf(cv.x - x), fabsf(cv.y - x)));
        m1 = fminf(m1, fminf(fabsf(cv.z - x), fabsf(cv.w - x)));
    }

    __shared__ float xm[4][64];
    xm[wave][lane] = fminf(m0, m1);
    __syncthreads();

    float psum = 0.f;
    if (wave == 0) {
        float m = fminf(fminf(xm[0][lane], xm[1][lane]),
                        fminf(xm[2][lane], xm[3][lane]));
        #pragma unroll
        for (int off = 32; off > 0; off >>= 1)
            m += __shfl_down(m, off, 64);
        psum = m;                                         // valid on lane 0
    }

    __shared__ int isfin;
    if (t == 0) {
        atomicExch(&partials[b], psum);                   // device-visible
        __threadfence();
        isfin = (atomicAdd(counter, 1u) == NBLK - 1);
    }
    __syncthreads();

    if (isfin) {
        __threadfence();
        // atomic reads (device coherence point); fixed order -> deterministic
        float sum = atomicAdd(&partials[t], 0.0f)
                  + atomicAdd(&partials[t + 256], 0.0f)
                  + atomicAdd(&partials[t + 512], 0.0f);
        #pragma unroll
        for (int off = 32; off > 0; off >>= 1)
            sum += __shfl_down(sum, off, 64);
        __shared__ float wsum[4];
        if ((t & 63) == 0) wsum[t >> 6] = sum;
        __syncthreads();
        if (t == 0)
            out[0] = ((wsum[0] + wsum[1]) + (wsum[2] + wsum[3])) * (1.0f / NPTS);
    }
}

extern "C" void kernel_launch(void* const* d_in, const int* in_sizes, int n_in,
                              void* d_out, int out_size, void* d_ws, size_t ws_size,
                              hipStream_t stream) {
    const float* pred   = (const float*)d_in[0];
    const float* target = (const float*)d_in[1];
    float* out = (float*)d_out;
    float* ws  = (float*)d_ws;
    float* partials = ws + WS_PARTIALS;
    unsigned int* counter = (unsigned int*)(ws + WS_COUNTER);

    dei_kernel<<<K0BLKS, THREADS, 0, stream>>>(pred, target, ws);
    chamfer_kernel<<<NBLK, THREADS, 0, stream>>>(ws, partials, counter, out);
}

// Round 7
// 39.019 us; speedup vs baseline: 1.7226x; 1.7226x over previous
//
#include <hip/hip_runtime.h>

typedef float f32x2 __attribute__((ext_vector_type(2)));

#define NPTS 8192
#define THREADS 256
#define PPT 16                  // points per thread (registers)
#define PPB (THREADS * PPT)     // 4096 points per block
#define PBLKS (NPTS / PPB)      // 2 point-blocks
#define NCHUNK 64               // candidate chunks
#define CAND (NPTS / NCHUNK)    // 128 candidates per chunk
#define WSROW (6 * NPTS)        // floats per chunk-slice: 49152
#define RED1BLKS 192            // 49152 / 256
#define NBLK (6 * PBLKS * NCHUNK)  // 768

// K1: block = (ch,dir,point-block,chunk). 128 candidates staged in LDS;
// each thread keeps 16 points + 16 running mins in registers. One
// ds_read_b128 feeds 64 pairs. Per 4 candidates x point: 2x f32x2 sub
// (v_pk_add_f32) + 2x v_min3(|.|,|.|) = 1.0 VALU per pair.
__global__ __launch_bounds__(THREADS) void chamfer_min_kernel(
    const float* __restrict__ pred, const float* __restrict__ target,
    float* __restrict__ ws)
{
    int b = blockIdx.x;
    const int ck  = b & (NCHUNK - 1); b >>= 6;
    const int pb  = b & (PBLKS - 1);  b >>= 1;
    const int dir = b & 1;            b >>= 1;
    const int ch  = b;                // 0..2

    const float* pts  = dir ? target : pred;   // dir=0: pred->target
    const float* cnds = dir ? pred   : target;

    __shared__ float4 s4[CAND / 4];            // 512 B
    const int t = threadIdx.x;
    if (t < CAND)
        ((float*)s4)[t] = cnds[(ck * CAND + t) * 3 + ch];

    f32x2 x2[PPT];
    float m[PPT];
    #pragma unroll
    for (int p = 0; p < PPT; ++p) {
        const float x = pts[(pb * PPB + p * THREADS + t) * 3 + ch];
        x2[p].x = x; x2[p].y = x;
        m[p] = 3.0e38f;
    }
    __syncthreads();

    #pragma unroll 4
    for (int k = 0; k < CAND / 4; ++k) {
        const float4 cv = s4[k];               // wave-uniform LDS broadcast
        f32x2 clo, chi;
        clo.x = cv.x; clo.y = cv.y;
        chi.x = cv.z; chi.y = cv.w;
        #pragma unroll
        for (int p = 0; p < PPT; ++p) {
            const f32x2 d0 = x2[p] - clo;      // v_pk_add_f32
            const f32x2 d1 = x2[p] - chi;
            m[p] = fminf(m[p], fminf(fabsf(d0.x), fabsf(d0.y)));  // v_min3
            m[p] = fminf(m[p], fminf(fabsf(d1.x), fabsf(d1.y)));
        }
    }

    float* w = ws + (size_t)ck * WSROW + (ch * 2 + dir) * NPTS + pb * PPB;
    #pragma unroll
    for (int p = 0; p < PPT; ++p)
        w[p * THREADS + t] = m[p];
}

// red1: 192 blocks x 256 thr; per point-slot min over the 64 chunk slices
// (coalesced, L2-resident), then block-sum -> 1 partial per block.
__global__ __launch_bounds__(THREADS) void chamfer_red1_kernel(
    const float* __restrict__ ws, float* __restrict__ partials)
{
    const int t = threadIdx.x;
    const int g = blockIdx.x * THREADS + t;    // 0..49151

    float mn = 3.0e38f;
    #pragma unroll 8
    for (int ck = 0; ck < NCHUNK; ++ck)
        mn = fminf(mn, ws[(size_t)ck * WSROW + g]);

    float sum = mn;
    #pragma unroll
    for (int off = 32; off > 0; off >>= 1)
        sum += __shfl_down(sum, off, 64);

    __shared__ float wsum[THREADS / 64];
    if ((t & 63) == 0) wsum[t >> 6] = sum;
    __syncthreads();
    if (t == 0) {
        float tot = 0.f;
        #pragma unroll
        for (int w = 0; w < THREADS / 64; ++w) tot += wsum[w];
        partials[blockIdx.x] = tot;
    }
}

// red2: one block sums 192 partials -> out = sum / NPTS.
__global__ __launch_bounds__(THREADS) void chamfer_red2_kernel(
    const float* __restrict__ partials, float* __restrict__ out)
{
    const int t = threadIdx.x;
    float sum = (t < RED1BLKS) ? partials[t] : 0.f;
    #pragma unroll
    for (int off = 32; off > 0; off >>= 1)
        sum += __shfl_down(sum, off, 64);

    __shared__ float wsum[4];
    if ((t & 63) == 0) wsum[t >> 6] = sum;
    __syncthreads();
    if (t == 0)
        out[0] = ((wsum[0] + wsum[1]) + (wsum[2] + wsum[3])) * (1.0f / NPTS);
}

extern "C" void kernel_launch(void* const* d_in, const int* in_sizes, int n_in,
                              void* d_out, int out_size, void* d_ws, size_t ws_size,
                              hipStream_t stream) {
    const float* pred   = (const float*)d_in[0];
    const float* target = (const float*)d_in[1];
    float* out = (float*)d_out;
    float* ws = (float*)d_ws;                               // [NCHUNK][6][NPTS]
    float* partials = ws + (size_t)NCHUNK * WSROW;          // [RED1BLKS]

    chamfer_min_kernel<<<NBLK, THREADS, 0, stream>>>(pred, target, ws);
    chamfer_red1_kernel<<<RED1BLKS, THREADS, 0, stream>>>(ws, partials);
    chamfer_red2_kernel<<<1, THREADS, 0, stream>>>(partials, out);
}